// Round 4
// baseline (257.055 us; speedup 1.0000x reference)
//
#include <hip/hip_runtime.h>

#define LOG2E 1.4426950408889634f

typedef float  f32x4 __attribute__((ext_vector_type(4)));
typedef int    i32x4 __attribute__((ext_vector_type(4)));
typedef short  s16x8 __attribute__((ext_vector_type(8)));

static __device__ __forceinline__ float exp2_fast(float x) {
#if __has_builtin(__builtin_amdgcn_exp2f)
    return __builtin_amdgcn_exp2f(x);
#else
    return exp2f(x);
#endif
}
static __device__ __forceinline__ unsigned short bf16_rne(float f) {
    unsigned u = __float_as_uint(f);
    u += 0x7FFFu + ((u >> 16) & 1u);
    return (unsigned short)(u >> 16);
}
// monotone unsigned key for float atomicMax
static __device__ __forceinline__ unsigned fkey(float f) {
    unsigned u = __float_as_uint(f);
    return (u & 0x80000000u) ? ~u : (u | 0x80000000u);
}
static __device__ __forceinline__ float fkey_dec(unsigned k) {
    return __uint_as_float((k & 0x80000000u) ? (k & 0x7fffffffu) : ~k);
}

// ---------------------------------------------------------------------------
// K1 (fused): adj -> bitmask (the big grid), plus piggybacked small preps:
// x f32->bf16, W* f32->bf16 transposed to [h][o][K], Mkey init.
// grid = 65536 x 256 (covers 4096^2 adj).
// ---------------------------------------------------------------------------
__global__ __launch_bounds__(256) void fused_prep(
    const int* __restrict__ adj,
    const float* __restrict__ xf,
    const float* __restrict__ W0, const float* __restrict__ W1,
    const float* __restrict__ W2,
    unsigned long long* __restrict__ bits,
    unsigned short* __restrict__ Xc,
    unsigned short* __restrict__ W0t, unsigned short* __restrict__ W1t,
    unsigned short* __restrict__ W2t, unsigned* __restrict__ Mkey)
{
    int gid = blockIdx.x * 256 + threadIdx.x;
    unsigned long long m = __ballot(adj[gid] != 0);
    if ((gid & 63) == 0) bits[gid >> 6] = m;

    if (gid < 524288) Xc[gid] = bf16_rne(xf[gid]);      // x: 4096x128
    if (gid < 12) Mkey[gid] = 0u;                        // key(-inf)=0
    if (gid < 32768) {                                   // W0: (4,128,64)
        int h = gid >> 13, d = (gid >> 6) & 127, o = gid & 63;
        W0t[(h * 64 + o) * 128 + d] = bf16_rne(W0[gid]);
    } else if (gid < 98304) {                            // W1: (4,256,64)
        int g = gid - 32768;
        int h = g >> 14, d = (g >> 6) & 255, o = g & 63;
        W1t[(h * 64 + o) * 256 + d] = bf16_rne(W1[g]);
    } else if (gid < 114688) {                           // W2: (1,256,64)
        int g = gid - 98304;
        int d = g >> 6, o = g & 63;
        W2t[o * 256 + d] = bf16_rne(W2[g]);
    }
}

// ---------------------------------------------------------------------------
// Shared GEMM epilogue: write hT[h][o][n] (bf16), el2/er2 (f32*log2e),
// and per-head er2-max via monotone-key atomicMax.
// ---------------------------------------------------------------------------
static __device__ __forceinline__ void gemm_epilogue(
    const f32x4* acc, const float* ab, int h, int nb, int c, int q, int lane,
    unsigned short* hT, float* el2, float* er2, unsigned* Mkey)
{
#pragma unroll
    for (int j = 0; j < 4; ++j) {
        unsigned d0 = (unsigned)bf16_rne(acc[j][0]) | ((unsigned)bf16_rne(acc[j][1]) << 16);
        unsigned d1 = (unsigned)bf16_rne(acc[j][2]) | ((unsigned)bf16_rne(acc[j][3]) << 16);
        unsigned short* dst = hT + ((size_t)h * 64 + j * 16 + c) * 4096 + nb + q * 4;
        ((unsigned*)dst)[0] = d0;
        ((unsigned*)dst)[1] = d1;
    }
    float elr[4] = {0,0,0,0}, err[4] = {0,0,0,0};
#pragma unroll
    for (int j = 0; j < 4; ++j) {
        float al = ab[j * 16 + c];
        float ar = ab[64 + j * 16 + c];
#pragma unroll
        for (int r = 0; r < 4; ++r) {
            elr[r] = fmaf(al, acc[j][r], elr[r]);
            err[r] = fmaf(ar, acc[j][r], err[r]);
        }
    }
#pragma unroll
    for (int m = 1; m <= 8; m <<= 1) {
#pragma unroll
        for (int r = 0; r < 4; ++r) {
            elr[r] += __shfl_xor(elr[r], m, 64);
            err[r] += __shfl_xor(err[r], m, 64);
        }
    }
    float rmax = -3.0e38f;
    if (c == 0) {
#pragma unroll
        for (int r = 0; r < 4; ++r) {
            int n = nb + q * 4 + r;
            float r2 = err[r] * LOG2E;
            el2[h * 4096 + n] = elr[r] * LOG2E;
            er2[h * 4096 + n] = r2;
            rmax = fmaxf(rmax, r2);
        }
    }
    rmax = fmaxf(rmax, __shfl_xor(rmax, 16, 64));
    rmax = fmaxf(rmax, __shfl_xor(rmax, 32, 64));
    if (lane == 0) atomicMax(&Mkey[h], fkey(rmax));
}

// ---------------------------------------------------------------------------
// K2 (layer 0): h = X @ W (MFMA 16x16x32 bf16) from bf16 X. grid (64, H).
// ---------------------------------------------------------------------------
__global__ __launch_bounds__(256) void gemm_elr(
    const unsigned short* __restrict__ X, int K,
    const unsigned short* __restrict__ Wt,   // [H][64][K] bf16
    const float* __restrict__ a,             // [H][128] f32
    unsigned short* __restrict__ hT,
    float* __restrict__ el2, float* __restrict__ er2,
    unsigned* __restrict__ Mkey)
{
    const int lane = threadIdx.x & 63, w = threadIdx.x >> 6;
    const int c = lane & 15, q = lane >> 4;
    const int h = blockIdx.y;
    const int nb = blockIdx.x * 64 + w * 16;
    const unsigned short* xrow = X + (size_t)(nb + c) * K + q * 8;
    const unsigned short* wb   = Wt + ((size_t)h * 64 + c) * K + q * 8;

    f32x4 acc[4] = {{0,0,0,0},{0,0,0,0},{0,0,0,0},{0,0,0,0}};
    for (int kk = 0; kk < K; kk += 32) {
        s16x8 af = *(const s16x8*)(xrow + kk);
#pragma unroll
        for (int j = 0; j < 4; ++j) {
            s16x8 bf = *(const s16x8*)(wb + (size_t)(j * 16) * K + kk);
            acc[j] = __builtin_amdgcn_mfma_f32_16x16x32_bf16(af, bf, acc[j], 0, 0, 0);
        }
    }
    gemm_epilogue(acc, a + h * 128, h, nb, c, q, lane, hT, el2, er2, Mkey);
}

// ---------------------------------------------------------------------------
// K2' (layers 1,2): same GEMM but A-fragments are built in-register from the
// previous layer's attention partials: v = (accP0+accP1)/(l0+l1), ELU, bf16.
// Input partials: KS=2, Hprev=4, HO=256 (fixed). grid (64, H). K must be 256.
// ---------------------------------------------------------------------------
__global__ __launch_bounds__(256) void gemm_comb(
    const float* __restrict__ accP, const float* __restrict__ lP,
    const unsigned short* __restrict__ Wt,   // [H][64][256] bf16
    const float* __restrict__ a,             // [H][128] f32
    unsigned short* __restrict__ hT,
    float* __restrict__ el2, float* __restrict__ er2,
    unsigned* __restrict__ Mkey)
{
    const int lane = threadIdx.x & 63, w = threadIdx.x >> 6;
    const int c = lane & 15, q = lane >> 4;
    const int h = blockIdx.y;
    const int nb = blockIdx.x * 64 + w * 16;
    const int n = nb + c;                    // A-row this lane loads
    const unsigned short* wb = Wt + ((size_t)h * 64 + c) * 256 + q * 8;

    // denominators of the 4 previous-layer heads for row n
    float rl[4];
#pragma unroll
    for (int hh = 0; hh < 4; ++hh)
        rl[hh] = 1.0f / (lP[(size_t)hh * 4096 + n] + lP[(size_t)(4 + hh) * 4096 + n]);
    const float* ap0 = accP + (size_t)n * 256;
    const float* ap1 = accP + (size_t)(4096 + n) * 256;

    f32x4 acc[4] = {{0,0,0,0},{0,0,0,0},{0,0,0,0},{0,0,0,0}};
    for (int kk = 0; kk < 256; kk += 32) {
        const int cb = q * 8 + kk;           // column base; cb..cb+7 in one head
        f32x4 s0a = *(const f32x4*)(ap0 + cb), s0b = *(const f32x4*)(ap0 + cb + 4);
        f32x4 s1a = *(const f32x4*)(ap1 + cb), s1b = *(const f32x4*)(ap1 + cb + 4);
        const float r = rl[cb >> 6];
        float v[8];
#pragma unroll
        for (int i = 0; i < 4; ++i) {
            v[i]     = (s0a[i] + s1a[i]) * r;
            v[i + 4] = (s0b[i] + s1b[i]) * r;
        }
        unsigned pd[4];
#pragma unroll
        for (int i = 0; i < 4; ++i) {
            float v0 = v[2 * i], v1 = v[2 * i + 1];
            v0 = (v0 < 0.f) ? exp2_fast(v0 * LOG2E) - 1.f : v0;   // ELU
            v1 = (v1 < 0.f) ? exp2_fast(v1 * LOG2E) - 1.f : v1;
            pd[i] = (unsigned)bf16_rne(v0) | ((unsigned)bf16_rne(v1) << 16);
        }
        union { unsigned u[4]; s16x8 s; } afu;
        afu.u[0] = pd[0]; afu.u[1] = pd[1]; afu.u[2] = pd[2]; afu.u[3] = pd[3];
        s16x8 af = afu.s;
#pragma unroll
        for (int j = 0; j < 4; ++j) {
            s16x8 bf = *(const s16x8*)(wb + (size_t)(j * 16) * 256 + kk);
            acc[j] = __builtin_amdgcn_mfma_f32_16x16x32_bf16(af, bf, acc[j], 0, 0, 0);
        }
    }
    gemm_epilogue(acc, a + h * 128, h, nb, c, q, lane, hT, el2, er2, Mkey);
}

// ---------------------------------------------------------------------------
// K3: fused masked-softmax attention, no rescaling.
//   p[n][m] = exp2( min(0, score2 - C2[n]) ) & adjbit,  p <= 1
//   numerator += p @ h (MFMA bf16); denominator via ones-column MFMA.
// Block: 4 waves x 16 rows = 64 rows, one head, one key segment.
// LDS: hT tile 64(o) x 256(m) bf16, stride 264. grid = (64, H, KS).
// ---------------------------------------------------------------------------
__global__ __launch_bounds__(256) void att_kernel(
    const unsigned short* __restrict__ hT,
    const float* __restrict__ el2g, const float* __restrict__ er2g,
    const unsigned* __restrict__ Mkey,
    const unsigned long long* __restrict__ bits,
    float* __restrict__ accP, float* __restrict__ lP,
    int H, int KPS, int HO)
{
    __shared__ unsigned short ldsH[64 * 264];
    __shared__ float ldsE[256];
    const int tid = threadIdx.x;
    const int lane = tid & 63, w = tid >> 6;
    const int c = lane & 15, q = lane >> 4, q8 = q * 8;
    const int h = blockIdx.y, ks = blockIdx.z;
    const int nb = blockIdx.x * 64 + w * 16;
    const int rowA = nb + c;

    const float M2 = fkey_dec(Mkey[h]);
    float e2 = el2g[h * 4096 + rowA];
    float xx = e2 + M2;
    float C2 = fmaxf(xx, 0.2f * xx);   // leaky(el2 + max er2) >= all row scores
    const float elA = e2 - C2;
    const float elB = fmaf(0.2f, e2, -C2);

    const char* bitrow = (const char*)bits + (size_t)rowA * 512 + (size_t)(KPS >> 3) * ks;

    s16x8 ones = {0,0,0,0,0,0,0,0};
    if (c == 0) {
#pragma unroll
        for (int i = 0; i < 8; ++i) ones[i] = (short)0x3F80;   // bf16 1.0, col 0
    }
    f32x4 acc[4] = {{0,0,0,0},{0,0,0,0},{0,0,0,0},{0,0,0,0}};
    f32x4 accl = {0,0,0,0};

    const unsigned short* hTh = hT + (size_t)h * 64 * 4096;
    const float* erh = er2g + h * 4096;
    const int tiles = KPS >> 8;

    for (int t = 0; t < tiles; ++t) {
        const int mabs = ks * KPS + t * 256;
#pragma unroll
        for (int i = 0; i < 8; ++i) {
            int cidx = i * 256 + tid;
            int o = cidx >> 5, seg = cidx & 31;
            i32x4 v = *(const i32x4*)(hTh + (size_t)o * 4096 + mabs + seg * 8);
            *(i32x4*)(ldsH + o * 264 + seg * 8) = v;
        }
        if (tid < 64)
            *(f32x4*)(ldsE + tid * 4) = *(const f32x4*)(erh + mabs + tid * 4);
        __syncthreads();

        i32x4 b0 = *(const i32x4*)(bitrow + t * 32);
        i32x4 b1 = *(const i32x4*)(bitrow + t * 32 + 16);
        int bw[8] = {b0[0], b0[1], b0[2], b0[3], b1[0], b1[1], b1[2], b1[3]};

#pragma unroll
        for (int cc = 0; cc < 8; ++cc) {
            const int kl = cc * 32 + q8;
            f32x4 ea = *(const f32x4*)(ldsE + kl);
            f32x4 eb = *(const f32x4*)(ldsE + kl + 4);
            const unsigned word = (unsigned)bw[cc];
            unsigned pd[4];
#pragma unroll
            for (int jj = 0; jj < 4; ++jj) {
                float er0 = (jj < 2) ? ea[2 * jj]     : eb[2 * jj - 4];
                float er1 = (jj < 2) ? ea[2 * jj + 1] : eb[2 * jj - 3];
                float s0 = fminf(fmaxf(elA + er0, fmaf(0.2f, er0, elB)), 0.f);
                float s1 = fminf(fmaxf(elA + er1, fmaf(0.2f, er1, elB)), 0.f);
                float p0 = exp2_fast(s0);
                float p1 = exp2_fast(s1);
                unsigned m0 = (unsigned)(-(int)((word >> (q8 + 2 * jj)) & 1u));
                unsigned m1 = (unsigned)(-(int)((word >> (q8 + 2 * jj + 1)) & 1u));
                unsigned u0 = __float_as_uint(p0) & m0;
                unsigned u1 = __float_as_uint(p1) & m1;
                pd[jj] = (u0 >> 16) | (u1 & 0xFFFF0000u);  // truncate-pack 2 bf16
            }
            union { unsigned u[4]; s16x8 s; } afu;
            afu.u[0] = pd[0]; afu.u[1] = pd[1]; afu.u[2] = pd[2]; afu.u[3] = pd[3];
            s16x8 af = afu.s;
            const unsigned short* lb = ldsH + c * 264 + kl;
#pragma unroll
            for (int j = 0; j < 4; ++j) {
                s16x8 bf = *(const s16x8*)(lb + (size_t)(j * 16) * 264);
                acc[j] = __builtin_amdgcn_mfma_f32_16x16x32_bf16(af, bf, acc[j], 0, 0, 0);
            }
            accl = __builtin_amdgcn_mfma_f32_16x16x32_bf16(af, ones, accl, 0, 0, 0);
        }
        __syncthreads();
    }
    float ls[4];
#pragma unroll
    for (int r = 0; r < 4; ++r) ls[r] = __shfl(accl[r], lane & 48, 64);

    float* ap = accP + ((size_t)ks * 4096 + nb + q * 4) * HO + h * 64 + c;
#pragma unroll
    for (int r = 0; r < 4; ++r)
#pragma unroll
        for (int j = 0; j < 4; ++j)
            ap[(size_t)r * HO + j * 16] = acc[j][r];
    if (c == 0) {
#pragma unroll
        for (int r = 0; r < 4; ++r)
            lP[((size_t)ks * H + h) * 4096 + nb + q * 4 + r] = ls[r];
    }
}

// ---------------------------------------------------------------------------
// K4: final combine (layer 2 only): KS=4, H=1, HO=64, f32 out, no ELU.
// ---------------------------------------------------------------------------
__global__ __launch_bounds__(256) void comb_final(
    const float* __restrict__ accP, const float* __restrict__ lP,
    float* __restrict__ outf)
{
    const int idx = blockIdx.x * 256 + threadIdx.x;
    const int n = idx >> 6, col = idx & 63;
    float s = 0.f, l = 0.f;
#pragma unroll
    for (int ks = 0; ks < 4; ++ks) {
        s += accP[((size_t)ks * 4096 + n) * 64 + col];
        l += lP[(size_t)ks * 4096 + n];
    }
    outf[idx] = s / l;
}

// ---------------------------------------------------------------------------
extern "C" void kernel_launch(void* const* d_in, const int* in_sizes, int n_in,
                              void* d_out, int out_size, void* d_ws, size_t ws_size,
                              hipStream_t stream)
{
    (void)in_sizes; (void)n_in; (void)out_size; (void)ws_size;
    const float* x   = (const float*)d_in[0];
    const int*   adj = (const int*)d_in[1];
    const float* W0  = (const float*)d_in[2];
    const float* a0  = (const float*)d_in[3];
    const float* W1  = (const float*)d_in[4];
    const float* a1  = (const float*)d_in[5];
    const float* W2  = (const float*)d_in[6];
    const float* a2  = (const float*)d_in[7];

    char* p = (char*)d_ws;                                   // ~13.5 MB used
    unsigned long long* bits = (unsigned long long*)(p + 0x000000);  // 2 MB
    unsigned short* hT  = (unsigned short*)(p + 0x200000);           // 2 MB
    unsigned short* Xc  = (unsigned short*)(p + 0x400000);           // 1 MB
    unsigned short* W0t = (unsigned short*)(p + 0x500000);           // 64 KB
    unsigned short* W1t = (unsigned short*)(p + 0x510000);           // 128 KB
    unsigned short* W2t = (unsigned short*)(p + 0x530000);           // 32 KB
    float*    el2  = (float*)(p + 0x538000);                         // 64 KB
    float*    er2  = (float*)(p + 0x548000);                         // 64 KB
    unsigned* Mkey = (unsigned*)(p + 0x558000);                      // 48 B
    float*    accP = (float*)(p + 0x560000);                         // 8 MB
    float*    lP   = (float*)(p + 0xD60000);                         // 128 KB

    fused_prep<<<65536, 256, 0, stream>>>(adj, x, W0, W1, W2,
                                          bits, Xc, W0t, W1t, W2t, Mkey);

    // layer 0: K=128, H=4
    gemm_elr<<<dim3(64, 4), 256, 0, stream>>>(Xc, 128, W0t, a0, hT, el2, er2, Mkey + 0);
    att_kernel<<<dim3(64, 4, 2), 256, 0, stream>>>(hT, el2, er2, Mkey + 0, bits, accP, lP, 4, 2048, 256);

    // layer 1: K=256, H=4 (combine fused into GEMM A-fragment load)
    gemm_comb<<<dim3(64, 4), 256, 0, stream>>>(accP, lP, W1t, a1, hT, el2, er2, Mkey + 4);
    att_kernel<<<dim3(64, 4, 2), 256, 0, stream>>>(hT, el2, er2, Mkey + 4, bits, accP, lP, 4, 2048, 256);

    // layer 2: K=256, H=1
    gemm_comb<<<dim3(64, 1), 256, 0, stream>>>(accP, lP, W2t, a2, hT, el2, er2, Mkey + 8);
    att_kernel<<<dim3(64, 1, 4), 256, 0, stream>>>(hT, el2, er2, Mkey + 8, bits, accP, lP, 1, 1024, 64);

    comb_final<<<1024, 256, 0, stream>>>(accP, lP, (float*)d_out);
}